// Round 5
// baseline (6062.022 us; speedup 1.0000x reference)
//
#include <hip/hip_runtime.h>
#include <stdint.h>

typedef unsigned short u16;
typedef __attribute__((ext_vector_type(8))) short bf16x8;
typedef __attribute__((ext_vector_type(4))) float fx4;
typedef __attribute__((ext_vector_type(2))) unsigned int u32x2;

#define MFMA16(a, b, c) __builtin_amdgcn_mfma_f32_16x16x32_bf16((a), (b), (c), 0, 0, 0)
// prevent the compiler from re-materializing weight loads inside the step loop
#define KEEP(x) asm volatile("" : "+v"(x))

// ---- workspace layout (bytes) ---- total 136265728 (< proven 144.7 MB)
// X <-> seq overlay: enc chunk k writes seq t in [64k,64k+64); zx chunk j reads
// X t in [64j,64j+64) and is launched before enc(j-1) -> disjoint, safe.
// FSEQ overlays the Z ring (Z dead after last enc chunk; dec runs after).
#define OFF_X      0u            // x bf16 [B=256][L=512][256]     67108864
#define OFF_SEQ    0u            // enc hidden bf16 [B][512][256] (overlay X)
#define OFF_ZRING  67108864u     // Z ring: 2 slots x 33554432     67108864
#define ZSLOT      33554432u     //   slot: [64 t][16 g][4 w][16 tile][64 lane]u32x2
#define OFF_FSEQ   67108864u     // dec hidden bf16 [B][64][256] (overlay ZRING)
#define OFF_ENCWT  134217728u    // enc_W^T bf16 [1024][256]         524288
#define OFF_ENCUT  134742016u    // enc_U^T bf16 [1024][256]         524288
#define OFF_CELLT  135266304u    // (cell_W+cell_U)^T bf16           524288
#define OFF_CONVKT 135790592u    // conv k^T bf16 [256][320]         163840
#define OFF_BWT    135954432u    // back_W^T bf16 [64][256]           32768
#define OFF_FWT    135987200u    // fore_W^T bf16 [32][256]           16384
#define OFF_CSAVE  136003584u    // c fp32 [16 g][4 w][64 lane][16]  262144

#define DYN_LDS (131072 + 16 * 264 * 2)   // 128 KB U s=6,7 + padded h buffer

__device__ __forceinline__ u16 f2bf(float f) {
    uint32_t u = __builtin_bit_cast(uint32_t, f);
    u += 0x7FFFu + ((u >> 16) & 1u);   // RNE
    return (u16)(u >> 16);
}
__device__ __forceinline__ float sigm(float x) { return 1.0f / (1.0f + __expf(-x)); }
__device__ __forceinline__ float tanh_f(float x) { return 1.0f - 2.0f / (__expf(2.0f * x) + 1.0f); }

// ---------------------------------------------------------------------------
__global__ void prep_kernel(const float* enc_W, const float* enc_U, const float* cell_W,
                            const float* cell_U, const float* conv_k, const float* back_W,
                            const float* fore_W, unsigned char* ws) {
    u16* encWt = (u16*)(ws + OFF_ENCWT);
    u16* encUt = (u16*)(ws + OFF_ENCUT);
    u16* cellT = (u16*)(ws + OFF_CELLT);
    u16* convKt = (u16*)(ws + OFF_CONVKT);
    u16* bwt = (u16*)(ws + OFF_BWT);
    u16* fwt = (u16*)(ws + OFF_FWT);
    int idx = blockIdx.x * blockDim.x + threadIdx.x;
    int stride = gridDim.x * blockDim.x;
    for (int i = idx; i < 262144; i += stride) {
        int n = i >> 8, k = i & 255;
        encWt[i] = f2bf(enc_W[k * 1024 + n]);
        encUt[i] = f2bf(enc_U[k * 1024 + n]);
        cellT[i] = f2bf(cell_W[k * 1024 + n] + cell_U[k * 1024 + n]);
    }
    for (int i = idx; i < 81920; i += stride) {
        int u = i / 320, rem = i - u * 320;
        convKt[i] = f2bf(conv_k[rem * 256 + u]);
    }
    for (int i = idx; i < 16384; i += stride) {
        int n = i >> 8, k = i & 255;
        bwt[i] = f2bf(back_W[k * 64 + n]);
    }
    for (int i = idx; i < 8192; i += stride) {
        int n = i >> 8, k = i & 255;
        fwt[i] = f2bf(fore_W[k * 32 + n]);
    }
}

// ---------------------------------------------------------------------------
// Conv1D(same,k=5)+bias+ReLU as MFMA GEMM (validated rounds 1-3)
__global__ __launch_bounds__(256) void conv_kernel(const float* __restrict__ in,
                                                   const float* __restrict__ conv_b,
                                                   unsigned char* ws) {
    const u16* kt = (const u16*)(ws + OFF_CONVKT);
    u16* xout = (u16*)(ws + OFF_X);
    int w = threadIdx.x >> 6, lane = threadIdx.x & 63;
    int m = lane & 15, q = lane >> 4;
    int mt = blockIdx.x * 4 + w;
    int r0 = mt * 16;
    int b = r0 >> 9;
    int l0 = r0 & 511;

    fx4 acc[16];
#pragma unroll
    for (int nt = 0; nt < 16; ++nt) acc[nt] = (fx4){0.f, 0.f, 0.f, 0.f};

#pragma unroll
    for (int s = 0; s < 10; ++s) {
        int k0 = s * 32 + q * 8;
        int kk = k0 >> 6, c = k0 & 63;
        int l2 = l0 + m + kk - 2;
        bf16x8 af = {0, 0, 0, 0, 0, 0, 0, 0};
        if (l2 >= 0 && l2 < 512) {
            const float* src = in + (((b << 9) + l2) << 6) + c;
            fx4 f0 = *(const fx4*)src;
            fx4 f1 = *(const fx4*)(src + 4);
            af[0] = (short)f2bf(f0[0]); af[1] = (short)f2bf(f0[1]);
            af[2] = (short)f2bf(f0[2]); af[3] = (short)f2bf(f0[3]);
            af[4] = (short)f2bf(f1[0]); af[5] = (short)f2bf(f1[1]);
            af[6] = (short)f2bf(f1[2]); af[7] = (short)f2bf(f1[3]);
        }
#pragma unroll
        for (int nt = 0; nt < 16; ++nt) {
            bf16x8 bf = *(const bf16x8*)(kt + (nt * 16 + m) * 320 + k0);
            acc[nt] = MFMA16(af, bf, acc[nt]);
        }
    }
#pragma unroll
    for (int nt = 0; nt < 16; ++nt) {
        int u = nt * 16 + m;
        float bias = conv_b[u];
#pragma unroll
        for (int r = 0; r < 4; ++r) {
            float v = acc[nt][r] + bias;
            v = v > 0.f ? v : 0.f;
            int row = r0 + q * 4 + r;
            xout[row * 256 + u] = f2bf(v);
        }
    }
}

// ---------------------------------------------------------------------------
// Z = X @ enc_W + enc_b for one 64-step chunk, stored bf16 tile-major in the
// fragment order the encoder consumes:
//   zslot[t_loc][g][w][tile=gate*4+j][lane] (u32x2 = 4 C-rows packed)
// WG = 4 waves; wave nq = gate; per WG: 2 timesteps x 16 batch rows x 1024 cols.
__global__ __launch_bounds__(256) void zx_kernel(const float* __restrict__ enc_b,
                                                 unsigned char* ws, int t0, int slot) {
    const u16* xbf = (const u16*)(ws + OFF_X);
    const u16* wt = (const u16*)(ws + OFF_ENCWT);
    unsigned char* zc = ws + OFF_ZRING + (size_t)slot * ZSLOT;
    int tid = threadIdx.x;
    int nq = tid >> 6, lane = tid & 63, m = lane & 15, q = lane >> 4;
    int bid = blockIdx.x;
    int tp = bid >> 4, g = bid & 15;     // tp in [0,32)
    int tl0 = tp * 2, b0 = g * 16;

    fx4 acc[2][16];
#pragma unroll
    for (int ts = 0; ts < 2; ++ts)
#pragma unroll
        for (int ntl = 0; ntl < 16; ++ntl) acc[ts][ntl] = (fx4){0.f, 0.f, 0.f, 0.f};

#pragma unroll
    for (int s = 0; s < 8; ++s) {
        bf16x8 a0 = *(const bf16x8*)(xbf + ((size_t)(b0 + m) * 512 + t0 + tl0) * 256 + s * 32 + q * 8);
        bf16x8 a1 = *(const bf16x8*)(xbf + ((size_t)(b0 + m) * 512 + t0 + tl0 + 1) * 256 + s * 32 + q * 8);
#pragma unroll
        for (int ntl = 0; ntl < 16; ++ntl) {
            bf16x8 bfg = *(const bf16x8*)(wt + (nq * 256 + ntl * 16 + m) * 256 + s * 32 + q * 8);
            acc[0][ntl] = MFMA16(a0, bfg, acc[0][ntl]);
            acc[1][ntl] = MFMA16(a1, bfg, acc[1][ntl]);
        }
    }

    float eb[16];
#pragma unroll
    for (int ntl = 0; ntl < 16; ++ntl) eb[ntl] = enc_b[nq * 256 + ntl * 16 + m];

#pragma unroll
    for (int ts = 0; ts < 2; ++ts) {
#pragma unroll
        for (int ntl = 0; ntl < 16; ++ntl) {
            int wp = ntl >> 2;                 // encoder wave owning these cols
            int tile = nq * 4 + (ntl & 3);     // encoder tile index (gate*4 + j)
            float v0 = acc[ts][ntl][0] + eb[ntl];
            float v1 = acc[ts][ntl][1] + eb[ntl];
            float v2 = acc[ts][ntl][2] + eb[ntl];
            float v3 = acc[ts][ntl][3] + eb[ntl];
            u32x2 d;
            d.x = (uint32_t)f2bf(v0) | ((uint32_t)f2bf(v1) << 16);
            d.y = (uint32_t)f2bf(v2) | ((uint32_t)f2bf(v3) << 16);
            // per (t,g,w): 16 tiles x 64 lanes x 8 B = 8192 B; coalesced per tile
            *(u32x2*)(zc + ((size_t)((tl0 + ts) * 16 + g) * 4 + wp) * 8192 + tile * 512 + lane * 8) = d;
        }
    }
}

// ---------------------------------------------------------------------------
// Encoder chunk: 64 steps starting at t0. 16 WGs (one per 16-row batch group),
// 4 waves; wave w owns 64 units (tiles gate*4+j, col = gate*256+w*64+j*16+m).
// U: s=0..5 in VGPRs (384 regs/wave), s=6..7 in LDS (128 KB). h exchange via
// LDS only. State carries across chunks via seq (h) and csave (c).
__global__ __launch_bounds__(256, 1) void enc_kernel(unsigned char* ws, int t0, int slot) {
    extern __shared__ char smem[];
    u16* lds_w = (u16*)smem;                    // [w][tile*2+ss][lane][8]
    u16* lds_h = (u16*)(smem + 131072);         // [16][264] padded

    int tid = threadIdx.x;
    int w = tid >> 6, lane = tid & 63, m = lane & 15, q = lane >> 4;
    int g = blockIdx.x;
    int b0 = g * 16;

    const u16* Ut = (const u16*)(ws + OFF_ENCUT);
    const unsigned char* zc = ws + OFF_ZRING + (size_t)slot * ZSLOT;
    u16* seq = (u16*)(ws + OFF_SEQ);
    float* csave = (float*)(ws + OFF_CSAVE);

    // U fragments: s=0..5 registers, s=6..7 staged to LDS
    bf16x8 wf[16][6];
#pragma unroll
    for (int nt = 0; nt < 16; ++nt) {
        int col = (nt >> 2) * 256 + w * 64 + (nt & 3) * 16 + m;
#pragma unroll
        for (int s = 0; s < 6; ++s) {
            wf[nt][s] = *(const bf16x8*)(Ut + col * 256 + s * 32 + q * 8);
            KEEP(wf[nt][s]);
        }
#pragma unroll
        for (int ss = 0; ss < 2; ++ss) {
            bf16x8 f = *(const bf16x8*)(Ut + col * 256 + (6 + ss) * 32 + q * 8);
            *(bf16x8*)(lds_w + (size_t)((w * 32 + nt * 2 + ss) * 64 + lane) * 8) = f;
        }
    }

    // h init: zero (chunk 0) or seq[t0-1]
    if (t0 == 0) {
        uint32_t* h32 = (uint32_t*)lds_h;
        for (int i = tid; i < 2112; i += 256) h32[i] = 0u;
    } else {
        int row = tid >> 4, u0 = (tid & 15) * 16;
        const u16* src = seq + ((size_t)(b0 + row) * 512 + (t0 - 1)) * 256 + u0;
        *(bf16x8*)(lds_h + row * 264 + u0) = *(const bf16x8*)src;
        *(bf16x8*)(lds_h + row * 264 + u0 + 8) = *(const bf16x8*)(src + 8);
    }
    // c init
    float c[16];
    if (t0 == 0) {
#pragma unroll
        for (int i = 0; i < 16; ++i) c[i] = 0.f;
    } else {
        const float* cs = csave + ((size_t)(g * 4 + w) * 64 + lane) * 16;
#pragma unroll
        for (int jr = 0; jr < 16; jr += 4) {
            fx4 cv = *(const fx4*)(cs + jr);
            c[jr] = cv[0]; c[jr + 1] = cv[1]; c[jr + 2] = cv[2]; c[jr + 3] = cv[3];
        }
    }
    __syncthreads();

    for (int tl = 0; tl < 64; ++tl) {
        bf16x8 ha[8];
#pragma unroll
        for (int s = 0; s < 8; ++s)
            ha[s] = *(const bf16x8*)(lds_h + m * 264 + s * 32 + q * 8);
        __syncthreads();   // all waves have read h_t

        const unsigned char* zrow = zc + ((size_t)(tl * 16 + g) * 4 + w) * 8192 + lane * 8;

#pragma unroll
        for (int j = 0; j < 4; ++j) {
            u32x2 zd[4];
#pragma unroll
            for (int gi = 0; gi < 4; ++gi)
                zd[gi] = *(const u32x2*)(zrow + (gi * 4 + j) * 512);

            fx4 acc[4];
#pragma unroll
            for (int gi = 0; gi < 4; ++gi) acc[gi] = (fx4){0.f, 0.f, 0.f, 0.f};
#pragma unroll
            for (int s = 0; s < 6; ++s)
#pragma unroll
                for (int gi = 0; gi < 4; ++gi)
                    acc[gi] = MFMA16(ha[s], wf[gi * 4 + j][s], acc[gi]);
#pragma unroll
            for (int ss = 0; ss < 2; ++ss)
#pragma unroll
                for (int gi = 0; gi < 4; ++gi) {
                    int nt = gi * 4 + j;
                    bf16x8 lwf = *(const bf16x8*)(lds_w + (size_t)((w * 32 + nt * 2 + ss) * 64 + lane) * 8);
                    acc[gi] = MFMA16(ha[6 + ss], lwf, acc[gi]);
                }
#pragma unroll
            for (int r = 0; r < 4; ++r) {
                uint32_t di = (r < 2) ? zd[0].x : zd[0].y;
                uint32_t df = (r < 2) ? zd[1].x : zd[1].y;
                uint32_t dg = (r < 2) ? zd[2].x : zd[2].y;
                uint32_t dz = (r < 2) ? zd[3].x : zd[3].y;
                float zi = __builtin_bit_cast(float, (r & 1) ? (di & 0xffff0000u) : (di << 16));
                float zf = __builtin_bit_cast(float, (r & 1) ? (df & 0xffff0000u) : (df << 16));
                float zg = __builtin_bit_cast(float, (r & 1) ? (dg & 0xffff0000u) : (dg << 16));
                float zo = __builtin_bit_cast(float, (r & 1) ? (dz & 0xffff0000u) : (dz << 16));
                float iv = acc[0][r] + zi, fv = acc[1][r] + zf;
                float gv = acc[2][r] + zg, ov = acc[3][r] + zo;
                float cv = sigm(fv) * c[j * 4 + r] + sigm(iv) * tanh_f(gv);
                c[j * 4 + r] = cv;
                lds_h[(q * 4 + r) * 264 + w * 64 + j * 16 + m] = f2bf(sigm(ov) * tanh_f(cv));
            }
        }
        __syncthreads();   // h_{t+1} complete

        // stream h_{t+1} to seq[b][t0+tl][u]
        {
            int row = tid >> 4, u0 = (tid & 15) * 16;
            bf16x8 h0 = *(const bf16x8*)(lds_h + row * 264 + u0);
            bf16x8 h1 = *(const bf16x8*)(lds_h + row * 264 + u0 + 8);
            u16* dst = seq + ((size_t)(b0 + row) * 512 + t0 + tl) * 256 + u0;
            *(bf16x8*)dst = h0;
            *(bf16x8*)(dst + 8) = h1;
        }
    }

    // persist c for the next chunk / decoder
    float* cs = csave + ((size_t)(g * 4 + w) * 64 + lane) * 16;
#pragma unroll
    for (int jr = 0; jr < 16; jr += 4)
        *(fx4*)(cs + jr) = (fx4){c[jr], c[jr + 1], c[jr + 2], c[jr + 3]};
}

// ---------------------------------------------------------------------------
// Decoder: 64 steps, input = previous h, weights = (cell_W+cell_U) combined.
__global__ __launch_bounds__(256, 1) void dec_kernel(const float* __restrict__ cell_b,
                                                     unsigned char* ws) {
    extern __shared__ char smem[];
    u16* lds_w = (u16*)smem;
    u16* lds_h = (u16*)(smem + 131072);

    int tid = threadIdx.x;
    int w = tid >> 6, lane = tid & 63, m = lane & 15, q = lane >> 4;
    int g = blockIdx.x;
    int b0 = g * 16;

    const u16* Ut = (const u16*)(ws + OFF_CELLT);
    const u16* seq = (const u16*)(ws + OFF_SEQ);
    u16* fseq = (u16*)(ws + OFF_FSEQ);
    const float* csave = (const float*)(ws + OFF_CSAVE);

    bf16x8 wf[16][6];
#pragma unroll
    for (int nt = 0; nt < 16; ++nt) {
        int col = (nt >> 2) * 256 + w * 64 + (nt & 3) * 16 + m;
#pragma unroll
        for (int s = 0; s < 6; ++s) {
            wf[nt][s] = *(const bf16x8*)(Ut + col * 256 + s * 32 + q * 8);
            KEEP(wf[nt][s]);
        }
#pragma unroll
        for (int ss = 0; ss < 2; ++ss) {
            bf16x8 f = *(const bf16x8*)(Ut + col * 256 + (6 + ss) * 32 + q * 8);
            *(bf16x8*)(lds_w + (size_t)((w * 32 + nt * 2 + ss) * 64 + lane) * 8) = f;
        }
    }
    float bi[16];
#pragma unroll
    for (int nt = 0; nt < 16; ++nt)
        bi[nt] = cell_b[(nt >> 2) * 256 + w * 64 + (nt & 3) * 16 + m];

    // h init = h_T = seq[.][511]
    {
        int row = tid >> 4, u0 = (tid & 15) * 16;
        const u16* src = seq + ((size_t)(b0 + row) * 512 + 511) * 256 + u0;
        *(bf16x8*)(lds_h + row * 264 + u0) = *(const bf16x8*)src;
        *(bf16x8*)(lds_h + row * 264 + u0 + 8) = *(const bf16x8*)(src + 8);
    }
    float c[16];
    {
        const float* cs = csave + ((size_t)(g * 4 + w) * 64 + lane) * 16;
#pragma unroll
        for (int jr = 0; jr < 16; jr += 4) {
            fx4 cv = *(const fx4*)(cs + jr);
            c[jr] = cv[0]; c[jr + 1] = cv[1]; c[jr + 2] = cv[2]; c[jr + 3] = cv[3];
        }
    }
    __syncthreads();

    for (int t = 0; t < 64; ++t) {
        bf16x8 ha[8];
#pragma unroll
        for (int s = 0; s < 8; ++s)
            ha[s] = *(const bf16x8*)(lds_h + m * 264 + s * 32 + q * 8);
        __syncthreads();

#pragma unroll
        for (int j = 0; j < 4; ++j) {
            fx4 acc[4];
#pragma unroll
            for (int gi = 0; gi < 4; ++gi) acc[gi] = (fx4){0.f, 0.f, 0.f, 0.f};
#pragma unroll
            for (int s = 0; s < 6; ++s)
#pragma unroll
                for (int gi = 0; gi < 4; ++gi)
                    acc[gi] = MFMA16(ha[s], wf[gi * 4 + j][s], acc[gi]);
#pragma unroll
            for (int ss = 0; ss < 2; ++ss)
#pragma unroll
                for (int gi = 0; gi < 4; ++gi) {
                    int nt = gi * 4 + j;
                    bf16x8 lwf = *(const bf16x8*)(lds_w + (size_t)((w * 32 + nt * 2 + ss) * 64 + lane) * 8);
                    acc[gi] = MFMA16(ha[6 + ss], lwf, acc[gi]);
                }
#pragma unroll
            for (int r = 0; r < 4; ++r) {
                float iv = acc[0][r] + bi[0 * 4 + j];
                float fv = acc[1][r] + bi[1 * 4 + j];
                float gv = acc[2][r] + bi[2 * 4 + j];
                float ov = acc[3][r] + bi[3 * 4 + j];
                float cv = sigm(fv) * c[j * 4 + r] + sigm(iv) * tanh_f(gv);
                c[j * 4 + r] = cv;
                lds_h[(q * 4 + r) * 264 + w * 64 + j * 16 + m] = f2bf(sigm(ov) * tanh_f(cv));
            }
        }
        __syncthreads();

        {
            int row = tid >> 4, u0 = (tid & 15) * 16;
            bf16x8 h0 = *(const bf16x8*)(lds_h + row * 264 + u0);
            bf16x8 h1 = *(const bf16x8*)(lds_h + row * 264 + u0 + 8);
            u16* dst = fseq + ((size_t)(b0 + row) * 64 + t) * 256 + u0;
            *(bf16x8*)dst = h0;
            *(bf16x8*)(dst + 8) = h1;
        }
    }
}

// ---------------------------------------------------------------------------
// out[b][s][col] = A[b][s][:] @ Bt[col][:] + bias[col]; A bf16 [B][seqT][256]
__global__ __launch_bounds__(256) void out_gemm(const u16* __restrict__ A,
                                                const u16* __restrict__ Bt,
                                                const float* __restrict__ bias,
                                                float* __restrict__ out,
                                                int ncols, int seqT) {
    int w = threadIdx.x >> 6, lane = threadIdx.x & 63, m = lane & 15, q = lane >> 4;
    int mt = blockIdx.x * 4 + w;
    int s = mt >> 4;
    int b0 = (mt & 15) * 16;
    bf16x8 af[8];
    const u16* Arow = A + ((size_t)(b0 + m) * seqT + s) * 256 + q * 8;
#pragma unroll
    for (int ss = 0; ss < 8; ++ss) af[ss] = *(const bf16x8*)(Arow + ss * 32);
    int ntiles = ncols >> 4;
    for (int nt = 0; nt < ntiles; ++nt) {
        fx4 acc = (fx4){0.f, 0.f, 0.f, 0.f};
#pragma unroll
        for (int ss = 0; ss < 8; ++ss) {
            bf16x8 bf = *(const bf16x8*)(Bt + (nt * 16 + m) * 256 + ss * 32 + q * 8);
            acc = MFMA16(af[ss], bf, acc);
        }
        int col = nt * 16 + m;
        float bv = bias[col];
#pragma unroll
        for (int r = 0; r < 4; ++r) {
            int b = b0 + q * 4 + r;
            out[((size_t)b * seqT + s) * ncols + col] = acc[r] + bv;
        }
    }
}

// ---------------------------------------------------------------------------
extern "C" void kernel_launch(void* const* d_in, const int* in_sizes, int n_in,
                              void* d_out, int out_size, void* d_ws, size_t ws_size,
                              hipStream_t stream) {
    const float* inputs = (const float*)d_in[0];
    const float* conv_k = (const float*)d_in[1];
    const float* conv_b = (const float*)d_in[2];
    const float* enc_W  = (const float*)d_in[3];
    const float* enc_U  = (const float*)d_in[4];
    const float* enc_b  = (const float*)d_in[5];
    const float* cell_W = (const float*)d_in[6];
    const float* cell_U = (const float*)d_in[7];
    const float* cell_b = (const float*)d_in[8];
    const float* fore_W = (const float*)d_in[9];
    const float* fore_b = (const float*)d_in[10];
    const float* back_W = (const float*)d_in[11];
    const float* back_b = (const float*)d_in[12];
    unsigned char* ws = (unsigned char*)d_ws;
    float* out = (float*)d_out;

    // opt-in >64KB dynamic LDS (attribute set; not a stream op, capture-safe)
    hipFuncSetAttribute((const void*)enc_kernel,
                        hipFuncAttributeMaxDynamicSharedMemorySize, DYN_LDS);
    hipFuncSetAttribute((const void*)dec_kernel,
                        hipFuncAttributeMaxDynamicSharedMemorySize, DYN_LDS);

    prep_kernel<<<1024, 256, 0, stream>>>(enc_W, enc_U, cell_W, cell_U, conv_k, back_W, fore_W, ws);
    conv_kernel<<<2048, 256, 0, stream>>>(inputs, conv_b, ws);

    // software pipeline: zx(k) ahead of enc(k-1); Z ring of 2 slots
    zx_kernel<<<512, 256, 0, stream>>>(enc_b, ws, 0, 0);
    zx_kernel<<<512, 256, 0, stream>>>(enc_b, ws, 64, 1);
    for (int k = 0; k < 8; ++k) {
        if (k >= 2) { /* slot k&1 was consumed by enc(k-2) already */ }
        enc_kernel<<<16, 256, DYN_LDS, stream>>>(ws, k * 64, k & 1);
        if (k + 2 < 8)
            zx_kernel<<<512, 256, 0, stream>>>(enc_b, ws, (k + 2) * 64, (k + 2) & 1);
    }

    dec_kernel<<<16, 256, DYN_LDS, stream>>>(cell_b, ws);

    // backcast: seq @ back_W -> out[b][l][64] at float offset 524288
    out_gemm<<<2048, 256, 0, stream>>>((const u16*)(ws + OFF_SEQ), (const u16*)(ws + OFF_BWT),
                                       back_b, out + 524288, 64, 512);
    // forecast: fseq @ fore_W -> out[b][j][32]
    out_gemm<<<256, 256, 0, stream>>>((const u16*)(ws + OFF_FSEQ), (const u16*)(ws + OFF_FWT),
                                      fore_b, out, 32, 64);
}

// Round 6
// 3780.310 us; speedup vs baseline: 1.6036x; 1.6036x over previous
//
#include <hip/hip_runtime.h>
#include <stdint.h>

typedef unsigned short u16;
typedef __attribute__((ext_vector_type(8))) short bf16x8;
typedef __attribute__((ext_vector_type(4))) float fx4;
typedef __attribute__((ext_vector_type(2))) unsigned int u32x2;

#define MFMA16(a, b, c) __builtin_amdgcn_mfma_f32_16x16x32_bf16((a), (b), (c), 0, 0, 0)
// Pin a 16B fragment into AGPRs (a0..a255). gfx950 MFMA reads A/B from AGPR
// directly, so these cost nothing in the loop. NEVER pin >256 regs to "v"
// (round-5 lesson: arch VGPRs cap at 256 -> scratch spill, 10 us/step).
#define KEEPA(x) asm volatile("" : "+a"(x))

// ---- workspace layout (bytes) ---- total 136265728 (< proven 144.7 MB)
// X <-> seq overlay: enc chunk k writes seq t in [64k,64k+64); zx chunk j reads
// X t in [64j,64j+64) and is launched before enc(j-1) -> disjoint, safe.
// FSEQ overlays the Z ring (Z dead after last enc chunk; dec runs after).
#define OFF_X      0u            // x bf16 [B=256][L=512][256]     67108864
#define OFF_SEQ    0u            // enc hidden bf16 [B][512][256] (overlay X)
#define OFF_ZRING  67108864u     // Z ring: 2 slots x 33554432     67108864
#define ZSLOT      33554432u     //   slot: [64 t][16 g][4 w][16 tile][64 lane]u32x2
#define OFF_FSEQ   67108864u     // dec hidden bf16 [B][64][256] (overlay ZRING)
#define OFF_ENCWT  134217728u    // enc_W^T bf16 [1024][256]         524288
#define OFF_ENCUT  134742016u    // enc_U^T bf16 [1024][256]         524288
#define OFF_CELLT  135266304u    // (cell_W+cell_U)^T bf16           524288
#define OFF_CONVKT 135790592u    // conv k^T bf16 [256][320]         163840
#define OFF_BWT    135954432u    // back_W^T bf16 [64][256]           32768
#define OFF_FWT    135987200u    // fore_W^T bf16 [32][256]           16384
#define OFF_CSAVE  136003584u    // c fp32 [16 g][4 w][64 lane][16]  262144

#define DYN_LDS (131072 + 16 * 264 * 2)   // 128 KB U s=6,7 + padded h buffer

__device__ __forceinline__ u16 f2bf(float f) {
    uint32_t u = __builtin_bit_cast(uint32_t, f);
    u += 0x7FFFu + ((u >> 16) & 1u);   // RNE
    return (u16)(u >> 16);
}
__device__ __forceinline__ float sigm(float x) { return 1.0f / (1.0f + __expf(-x)); }
__device__ __forceinline__ float tanh_f(float x) { return 1.0f - 2.0f / (__expf(2.0f * x) + 1.0f); }

// ---------------------------------------------------------------------------
__global__ void prep_kernel(const float* enc_W, const float* enc_U, const float* cell_W,
                            const float* cell_U, const float* conv_k, const float* back_W,
                            const float* fore_W, unsigned char* ws) {
    u16* encWt = (u16*)(ws + OFF_ENCWT);
    u16* encUt = (u16*)(ws + OFF_ENCUT);
    u16* cellT = (u16*)(ws + OFF_CELLT);
    u16* convKt = (u16*)(ws + OFF_CONVKT);
    u16* bwt = (u16*)(ws + OFF_BWT);
    u16* fwt = (u16*)(ws + OFF_FWT);
    int idx = blockIdx.x * blockDim.x + threadIdx.x;
    int stride = gridDim.x * blockDim.x;
    for (int i = idx; i < 262144; i += stride) {
        int n = i >> 8, k = i & 255;
        encWt[i] = f2bf(enc_W[k * 1024 + n]);
        encUt[i] = f2bf(enc_U[k * 1024 + n]);
        cellT[i] = f2bf(cell_W[k * 1024 + n] + cell_U[k * 1024 + n]);
    }
    for (int i = idx; i < 81920; i += stride) {
        int u = i / 320, rem = i - u * 320;
        convKt[i] = f2bf(conv_k[rem * 256 + u]);
    }
    for (int i = idx; i < 16384; i += stride) {
        int n = i >> 8, k = i & 255;
        bwt[i] = f2bf(back_W[k * 64 + n]);
    }
    for (int i = idx; i < 8192; i += stride) {
        int n = i >> 8, k = i & 255;
        fwt[i] = f2bf(fore_W[k * 32 + n]);
    }
}

// ---------------------------------------------------------------------------
// Conv1D(same,k=5)+bias+ReLU as MFMA GEMM (validated rounds 1-3)
__global__ __launch_bounds__(256) void conv_kernel(const float* __restrict__ in,
                                                   const float* __restrict__ conv_b,
                                                   unsigned char* ws) {
    const u16* kt = (const u16*)(ws + OFF_CONVKT);
    u16* xout = (u16*)(ws + OFF_X);
    int w = threadIdx.x >> 6, lane = threadIdx.x & 63;
    int m = lane & 15, q = lane >> 4;
    int mt = blockIdx.x * 4 + w;
    int r0 = mt * 16;
    int b = r0 >> 9;
    int l0 = r0 & 511;

    fx4 acc[16];
#pragma unroll
    for (int nt = 0; nt < 16; ++nt) acc[nt] = (fx4){0.f, 0.f, 0.f, 0.f};

#pragma unroll
    for (int s = 0; s < 10; ++s) {
        int k0 = s * 32 + q * 8;
        int kk = k0 >> 6, c = k0 & 63;
        int l2 = l0 + m + kk - 2;
        bf16x8 af = {0, 0, 0, 0, 0, 0, 0, 0};
        if (l2 >= 0 && l2 < 512) {
            const float* src = in + (((b << 9) + l2) << 6) + c;
            fx4 f0 = *(const fx4*)src;
            fx4 f1 = *(const fx4*)(src + 4);
            af[0] = (short)f2bf(f0[0]); af[1] = (short)f2bf(f0[1]);
            af[2] = (short)f2bf(f0[2]); af[3] = (short)f2bf(f0[3]);
            af[4] = (short)f2bf(f1[0]); af[5] = (short)f2bf(f1[1]);
            af[6] = (short)f2bf(f1[2]); af[7] = (short)f2bf(f1[3]);
        }
#pragma unroll
        for (int nt = 0; nt < 16; ++nt) {
            bf16x8 bf = *(const bf16x8*)(kt + (nt * 16 + m) * 320 + k0);
            acc[nt] = MFMA16(af, bf, acc[nt]);
        }
    }
#pragma unroll
    for (int nt = 0; nt < 16; ++nt) {
        int u = nt * 16 + m;
        float bias = conv_b[u];
#pragma unroll
        for (int r = 0; r < 4; ++r) {
            float v = acc[nt][r] + bias;
            v = v > 0.f ? v : 0.f;
            int row = r0 + q * 4 + r;
            xout[row * 256 + u] = f2bf(v);
        }
    }
}

// ---------------------------------------------------------------------------
// Z = X @ enc_W + enc_b for one 64-step chunk, stored bf16 tile-major in the
// fragment order the encoder consumes (validated round 5).
__global__ __launch_bounds__(256) void zx_kernel(const float* __restrict__ enc_b,
                                                 unsigned char* ws, int t0, int slot) {
    const u16* xbf = (const u16*)(ws + OFF_X);
    const u16* wt = (const u16*)(ws + OFF_ENCWT);
    unsigned char* zc = ws + OFF_ZRING + (size_t)slot * ZSLOT;
    int tid = threadIdx.x;
    int nq = tid >> 6, lane = tid & 63, m = lane & 15, q = lane >> 4;
    int bid = blockIdx.x;
    int tp = bid >> 4, g = bid & 15;     // tp in [0,32)
    int tl0 = tp * 2, b0 = g * 16;

    fx4 acc[2][16];
#pragma unroll
    for (int ts = 0; ts < 2; ++ts)
#pragma unroll
        for (int ntl = 0; ntl < 16; ++ntl) acc[ts][ntl] = (fx4){0.f, 0.f, 0.f, 0.f};

#pragma unroll
    for (int s = 0; s < 8; ++s) {
        bf16x8 a0 = *(const bf16x8*)(xbf + ((size_t)(b0 + m) * 512 + t0 + tl0) * 256 + s * 32 + q * 8);
        bf16x8 a1 = *(const bf16x8*)(xbf + ((size_t)(b0 + m) * 512 + t0 + tl0 + 1) * 256 + s * 32 + q * 8);
#pragma unroll
        for (int ntl = 0; ntl < 16; ++ntl) {
            bf16x8 bfg = *(const bf16x8*)(wt + (nq * 256 + ntl * 16 + m) * 256 + s * 32 + q * 8);
            acc[0][ntl] = MFMA16(a0, bfg, acc[0][ntl]);
            acc[1][ntl] = MFMA16(a1, bfg, acc[1][ntl]);
        }
    }

    float eb[16];
#pragma unroll
    for (int ntl = 0; ntl < 16; ++ntl) eb[ntl] = enc_b[nq * 256 + ntl * 16 + m];

#pragma unroll
    for (int ts = 0; ts < 2; ++ts) {
#pragma unroll
        for (int ntl = 0; ntl < 16; ++ntl) {
            int wp = ntl >> 2;                 // encoder wave owning these cols
            int tile = nq * 4 + (ntl & 3);     // encoder tile index (gate*4 + j)
            float v0 = acc[ts][ntl][0] + eb[ntl];
            float v1 = acc[ts][ntl][1] + eb[ntl];
            float v2 = acc[ts][ntl][2] + eb[ntl];
            float v3 = acc[ts][ntl][3] + eb[ntl];
            u32x2 d;
            d.x = (uint32_t)f2bf(v0) | ((uint32_t)f2bf(v1) << 16);
            d.y = (uint32_t)f2bf(v2) | ((uint32_t)f2bf(v3) << 16);
            *(u32x2*)(zc + ((size_t)((tl0 + ts) * 16 + g) * 4 + wp) * 8192 + tile * 512 + lane * 8) = d;
        }
    }
}

// ---------------------------------------------------------------------------
// Encoder chunk: 64 steps from t0. 16 WGs (one per 16-row batch group), 4
// waves; wave w owns 64 units (tiles gate*4+j, col = gate*256+w*64+j*16+m).
// U placement per wave: s=0..3 AGPR (256 regs, "a"-pinned), s=4..5 VGPR
// (unpinned, ~128 regs), s=6..7 LDS (128 KB). h exchange via LDS only.
__global__ __launch_bounds__(256, 1) void enc_kernel(unsigned char* ws, int t0, int slot) {
    extern __shared__ char smem[];
    u16* lds_w = (u16*)smem;                    // [w][tile*2+ss][lane][8]
    u16* lds_h = (u16*)(smem + 131072);         // [16][264] padded

    int tid = threadIdx.x;
    int w = tid >> 6, lane = tid & 63, m = lane & 15, q = lane >> 4;
    int g = blockIdx.x;
    int b0 = g * 16;

    const u16* Ut = (const u16*)(ws + OFF_ENCUT);
    const unsigned char* zc = ws + OFF_ZRING + (size_t)slot * ZSLOT;
    u16* seq = (u16*)(ws + OFF_SEQ);
    float* csave = (float*)(ws + OFF_CSAVE);

    bf16x8 wa[16][4];   // s=0..3 -> AGPRs
    bf16x8 wv[16][2];   // s=4..5 -> VGPRs (allocator's choice, fits in 256)
#pragma unroll
    for (int nt = 0; nt < 16; ++nt) {
        int col = (nt >> 2) * 256 + w * 64 + (nt & 3) * 16 + m;
#pragma unroll
        for (int s = 0; s < 4; ++s) {
            wa[nt][s] = *(const bf16x8*)(Ut + col * 256 + s * 32 + q * 8);
            KEEPA(wa[nt][s]);
        }
#pragma unroll
        for (int s = 0; s < 2; ++s)
            wv[nt][s] = *(const bf16x8*)(Ut + col * 256 + (4 + s) * 32 + q * 8);
#pragma unroll
        for (int ss = 0; ss < 2; ++ss) {
            bf16x8 f = *(const bf16x8*)(Ut + col * 256 + (6 + ss) * 32 + q * 8);
            *(bf16x8*)(lds_w + (size_t)((w * 32 + nt * 2 + ss) * 64 + lane) * 8) = f;
        }
    }

    // h init: zero (chunk 0) or seq[t0-1]
    if (t0 == 0) {
        uint32_t* h32 = (uint32_t*)lds_h;
        for (int i = tid; i < 2112; i += 256) h32[i] = 0u;
    } else {
        int row = tid >> 4, u0 = (tid & 15) * 16;
        const u16* src = seq + ((size_t)(b0 + row) * 512 + (t0 - 1)) * 256 + u0;
        *(bf16x8*)(lds_h + row * 264 + u0) = *(const bf16x8*)src;
        *(bf16x8*)(lds_h + row * 264 + u0 + 8) = *(const bf16x8*)(src + 8);
    }
    // c init
    float c[16];
    if (t0 == 0) {
#pragma unroll
        for (int i = 0; i < 16; ++i) c[i] = 0.f;
    } else {
        const float* cs = csave + ((size_t)(g * 4 + w) * 64 + lane) * 16;
#pragma unroll
        for (int jr = 0; jr < 16; jr += 4) {
            fx4 cv = *(const fx4*)(cs + jr);
            c[jr] = cv[0]; c[jr + 1] = cv[1]; c[jr + 2] = cv[2]; c[jr + 3] = cv[3];
        }
    }
    __syncthreads();

    for (int tl = 0; tl < 64; ++tl) {
        bf16x8 ha[8];
#pragma unroll
        for (int s = 0; s < 8; ++s)
            ha[s] = *(const bf16x8*)(lds_h + m * 264 + s * 32 + q * 8);
        __syncthreads();   // all waves have read h_t

        const unsigned char* zrow = zc + ((size_t)(tl * 16 + g) * 4 + w) * 8192 + lane * 8;

#pragma unroll
        for (int j = 0; j < 4; ++j) {
            u32x2 zd[4];
#pragma unroll
            for (int gi = 0; gi < 4; ++gi)
                zd[gi] = *(const u32x2*)(zrow + (gi * 4 + j) * 512);

            fx4 acc[4];
#pragma unroll
            for (int gi = 0; gi < 4; ++gi) acc[gi] = (fx4){0.f, 0.f, 0.f, 0.f};
#pragma unroll
            for (int s = 0; s < 4; ++s)
#pragma unroll
                for (int gi = 0; gi < 4; ++gi)
                    acc[gi] = MFMA16(ha[s], wa[gi * 4 + j][s], acc[gi]);
#pragma unroll
            for (int s = 0; s < 2; ++s)
#pragma unroll
                for (int gi = 0; gi < 4; ++gi)
                    acc[gi] = MFMA16(ha[4 + s], wv[gi * 4 + j][s], acc[gi]);
#pragma unroll
            for (int ss = 0; ss < 2; ++ss)
#pragma unroll
                for (int gi = 0; gi < 4; ++gi) {
                    int nt = gi * 4 + j;
                    bf16x8 lwf = *(const bf16x8*)(lds_w + (size_t)((w * 32 + nt * 2 + ss) * 64 + lane) * 8);
                    acc[gi] = MFMA16(ha[6 + ss], lwf, acc[gi]);
                }
#pragma unroll
            for (int r = 0; r < 4; ++r) {
                uint32_t di = (r < 2) ? zd[0].x : zd[0].y;
                uint32_t df = (r < 2) ? zd[1].x : zd[1].y;
                uint32_t dg = (r < 2) ? zd[2].x : zd[2].y;
                uint32_t dz = (r < 2) ? zd[3].x : zd[3].y;
                float zi = __builtin_bit_cast(float, (r & 1) ? (di & 0xffff0000u) : (di << 16));
                float zf = __builtin_bit_cast(float, (r & 1) ? (df & 0xffff0000u) : (df << 16));
                float zg = __builtin_bit_cast(float, (r & 1) ? (dg & 0xffff0000u) : (dg << 16));
                float zo = __builtin_bit_cast(float, (r & 1) ? (dz & 0xffff0000u) : (dz << 16));
                float iv = acc[0][r] + zi, fv = acc[1][r] + zf;
                float gv = acc[2][r] + zg, ov = acc[3][r] + zo;
                float cv = sigm(fv) * c[j * 4 + r] + sigm(iv) * tanh_f(gv);
                c[j * 4 + r] = cv;
                lds_h[(q * 4 + r) * 264 + w * 64 + j * 16 + m] = f2bf(sigm(ov) * tanh_f(cv));
            }
        }
        __syncthreads();   // h_{t+1} complete

        // stream h_{t+1} to seq[b][t0+tl][u]
        {
            int row = tid >> 4, u0 = (tid & 15) * 16;
            bf16x8 h0 = *(const bf16x8*)(lds_h + row * 264 + u0);
            bf16x8 h1 = *(const bf16x8*)(lds_h + row * 264 + u0 + 8);
            u16* dst = seq + ((size_t)(b0 + row) * 512 + t0 + tl) * 256 + u0;
            *(bf16x8*)dst = h0;
            *(bf16x8*)(dst + 8) = h1;
        }
    }

    // persist c for the next chunk / decoder
    float* cs = csave + ((size_t)(g * 4 + w) * 64 + lane) * 16;
#pragma unroll
    for (int jr = 0; jr < 16; jr += 4)
        *(fx4*)(cs + jr) = (fx4){c[jr], c[jr + 1], c[jr + 2], c[jr + 3]};
}

// ---------------------------------------------------------------------------
// Decoder: 64 steps, input = previous h, weights = (cell_W+cell_U) combined.
// Same register placement scheme as enc_kernel.
__global__ __launch_bounds__(256, 1) void dec_kernel(const float* __restrict__ cell_b,
                                                     unsigned char* ws) {
    extern __shared__ char smem[];
    u16* lds_w = (u16*)smem;
    u16* lds_h = (u16*)(smem + 131072);

    int tid = threadIdx.x;
    int w = tid >> 6, lane = tid & 63, m = lane & 15, q = lane >> 4;
    int g = blockIdx.x;
    int b0 = g * 16;

    const u16* Ut = (const u16*)(ws + OFF_CELLT);
    const u16* seq = (const u16*)(ws + OFF_SEQ);
    u16* fseq = (u16*)(ws + OFF_FSEQ);
    const float* csave = (const float*)(ws + OFF_CSAVE);

    bf16x8 wa[16][4];
    bf16x8 wv[16][2];
#pragma unroll
    for (int nt = 0; nt < 16; ++nt) {
        int col = (nt >> 2) * 256 + w * 64 + (nt & 3) * 16 + m;
#pragma unroll
        for (int s = 0; s < 4; ++s) {
            wa[nt][s] = *(const bf16x8*)(Ut + col * 256 + s * 32 + q * 8);
            KEEPA(wa[nt][s]);
        }
#pragma unroll
        for (int s = 0; s < 2; ++s)
            wv[nt][s] = *(const bf16x8*)(Ut + col * 256 + (4 + s) * 32 + q * 8);
#pragma unroll
        for (int ss = 0; ss < 2; ++ss) {
            bf16x8 f = *(const bf16x8*)(Ut + col * 256 + (6 + ss) * 32 + q * 8);
            *(bf16x8*)(lds_w + (size_t)((w * 32 + nt * 2 + ss) * 64 + lane) * 8) = f;
        }
    }
    float bi[16];
#pragma unroll
    for (int nt = 0; nt < 16; ++nt)
        bi[nt] = cell_b[(nt >> 2) * 256 + w * 64 + (nt & 3) * 16 + m];

    // h init = h_T = seq[.][511]
    {
        int row = tid >> 4, u0 = (tid & 15) * 16;
        const u16* src = seq + ((size_t)(b0 + row) * 512 + 511) * 256 + u0;
        *(bf16x8*)(lds_h + row * 264 + u0) = *(const bf16x8*)src;
        *(bf16x8*)(lds_h + row * 264 + u0 + 8) = *(const bf16x8*)(src + 8);
    }
    float c[16];
    {
        const float* cs = csave + ((size_t)(g * 4 + w) * 64 + lane) * 16;
#pragma unroll
        for (int jr = 0; jr < 16; jr += 4) {
            fx4 cv = *(const fx4*)(cs + jr);
            c[jr] = cv[0]; c[jr + 1] = cv[1]; c[jr + 2] = cv[2]; c[jr + 3] = cv[3];
        }
    }
    __syncthreads();

    for (int t = 0; t < 64; ++t) {
        bf16x8 ha[8];
#pragma unroll
        for (int s = 0; s < 8; ++s)
            ha[s] = *(const bf16x8*)(lds_h + m * 264 + s * 32 + q * 8);
        __syncthreads();

#pragma unroll
        for (int j = 0; j < 4; ++j) {
            fx4 acc[4];
#pragma unroll
            for (int gi = 0; gi < 4; ++gi) acc[gi] = (fx4){0.f, 0.f, 0.f, 0.f};
#pragma unroll
            for (int s = 0; s < 4; ++s)
#pragma unroll
                for (int gi = 0; gi < 4; ++gi)
                    acc[gi] = MFMA16(ha[s], wa[gi * 4 + j][s], acc[gi]);
#pragma unroll
            for (int s = 0; s < 2; ++s)
#pragma unroll
                for (int gi = 0; gi < 4; ++gi)
                    acc[gi] = MFMA16(ha[4 + s], wv[gi * 4 + j][s], acc[gi]);
#pragma unroll
            for (int ss = 0; ss < 2; ++ss)
#pragma unroll
                for (int gi = 0; gi < 4; ++gi) {
                    int nt = gi * 4 + j;
                    bf16x8 lwf = *(const bf16x8*)(lds_w + (size_t)((w * 32 + nt * 2 + ss) * 64 + lane) * 8);
                    acc[gi] = MFMA16(ha[6 + ss], lwf, acc[gi]);
                }
#pragma unroll
            for (int r = 0; r < 4; ++r) {
                float iv = acc[0][r] + bi[0 * 4 + j];
                float fv = acc[1][r] + bi[1 * 4 + j];
                float gv = acc[2][r] + bi[2 * 4 + j];
                float ov = acc[3][r] + bi[3 * 4 + j];
                float cv = sigm(fv) * c[j * 4 + r] + sigm(iv) * tanh_f(gv);
                c[j * 4 + r] = cv;
                lds_h[(q * 4 + r) * 264 + w * 64 + j * 16 + m] = f2bf(sigm(ov) * tanh_f(cv));
            }
        }
        __syncthreads();

        {
            int row = tid >> 4, u0 = (tid & 15) * 16;
            bf16x8 h0 = *(const bf16x8*)(lds_h + row * 264 + u0);
            bf16x8 h1 = *(const bf16x8*)(lds_h + row * 264 + u0 + 8);
            u16* dst = fseq + ((size_t)(b0 + row) * 64 + t) * 256 + u0;
            *(bf16x8*)dst = h0;
            *(bf16x8*)(dst + 8) = h1;
        }
    }
}

// ---------------------------------------------------------------------------
// out[b][s][col] = A[b][s][:] @ Bt[col][:] + bias[col]; A bf16 [B][seqT][256]
__global__ __launch_bounds__(256) void out_gemm(const u16* __restrict__ A,
                                                const u16* __restrict__ Bt,
                                                const float* __restrict__ bias,
                                                float* __restrict__ out,
                                                int ncols, int seqT) {
    int w = threadIdx.x >> 6, lane = threadIdx.x & 63, m = lane & 15, q = lane >> 4;
    int mt = blockIdx.x * 4 + w;
    int s = mt >> 4;
    int b0 = (mt & 15) * 16;
    bf16x8 af[8];
    const u16* Arow = A + ((size_t)(b0 + m) * seqT + s) * 256 + q * 8;
#pragma unroll
    for (int ss = 0; ss < 8; ++ss) af[ss] = *(const bf16x8*)(Arow + ss * 32);
    int ntiles = ncols >> 4;
    for (int nt = 0; nt < ntiles; ++nt) {
        fx4 acc = (fx4){0.f, 0.f, 0.f, 0.f};
#pragma unroll
        for (int ss = 0; ss < 8; ++ss) {
            bf16x8 bf = *(const bf16x8*)(Bt + (nt * 16 + m) * 256 + ss * 32 + q * 8);
            acc = MFMA16(af[ss], bf, acc);
        }
        int col = nt * 16 + m;
        float bv = bias[col];
#pragma unroll
        for (int r = 0; r < 4; ++r) {
            int b = b0 + q * 4 + r;
            out[((size_t)b * seqT + s) * ncols + col] = acc[r] + bv;
        }
    }
}

// ---------------------------------------------------------------------------
extern "C" void kernel_launch(void* const* d_in, const int* in_sizes, int n_in,
                              void* d_out, int out_size, void* d_ws, size_t ws_size,
                              hipStream_t stream) {
    const float* inputs = (const float*)d_in[0];
    const float* conv_k = (const float*)d_in[1];
    const float* conv_b = (const float*)d_in[2];
    const float* enc_W  = (const float*)d_in[3];
    const float* enc_U  = (const float*)d_in[4];
    const float* enc_b  = (const float*)d_in[5];
    const float* cell_W = (const float*)d_in[6];
    const float* cell_U = (const float*)d_in[7];
    const float* cell_b = (const float*)d_in[8];
    const float* fore_W = (const float*)d_in[9];
    const float* fore_b = (const float*)d_in[10];
    const float* back_W = (const float*)d_in[11];
    const float* back_b = (const float*)d_in[12];
    unsigned char* ws = (unsigned char*)d_ws;
    float* out = (float*)d_out;

    // opt-in >64KB dynamic LDS (attribute set; not a stream op, capture-safe)
    hipFuncSetAttribute((const void*)enc_kernel,
                        hipFuncAttributeMaxDynamicSharedMemorySize, DYN_LDS);
    hipFuncSetAttribute((const void*)dec_kernel,
                        hipFuncAttributeMaxDynamicSharedMemorySize, DYN_LDS);

    prep_kernel<<<1024, 256, 0, stream>>>(enc_W, enc_U, cell_W, cell_U, conv_k, back_W, fore_W, ws);
    conv_kernel<<<2048, 256, 0, stream>>>(inputs, conv_b, ws);

    // software pipeline: zx(k) ahead of enc(k-1); Z ring of 2 slots.
    // Stream order guarantees: zx(k) precedes enc(k); zx(k+2) (same slot as
    // enc(k)) is launched after enc(k), so it can't overwrite a live slot.
    zx_kernel<<<512, 256, 0, stream>>>(enc_b, ws, 0, 0);
    zx_kernel<<<512, 256, 0, stream>>>(enc_b, ws, 64, 1);
    for (int k = 0; k < 8; ++k) {
        enc_kernel<<<16, 256, DYN_LDS, stream>>>(ws, k * 64, k & 1);
        if (k + 2 < 8)
            zx_kernel<<<512, 256, 0, stream>>>(enc_b, ws, (k + 2) * 64, (k + 2) & 1);
    }

    dec_kernel<<<16, 256, DYN_LDS, stream>>>(cell_b, ws);

    // backcast: seq @ back_W -> out[b][l][64] at float offset 524288
    out_gemm<<<2048, 256, 0, stream>>>((const u16*)(ws + OFF_SEQ), (const u16*)(ws + OFF_BWT),
                                       back_b, out + 524288, 64, 512);
    // forecast: fseq @ fore_W -> out[b][j][32]
    out_gemm<<<256, 256, 0, stream>>>((const u16*)(ws + OFF_FSEQ), (const u16*)(ws + OFF_FWT),
                                      fore_b, out, 32, 64);
}